// Round 4
// baseline (1547.018 us; speedup 1.0000x reference)
//
#include <hip/hip_runtime.h>

// Sizes (fixed for this problem)
#define T_TOK 1024
#define H_DIM 2048
#define E_NUM 32
#define I_DIM 1024
#define IS_DIM 2048

typedef float  f32x4 __attribute__((ext_vector_type(4)));
typedef short  s16x8 __attribute__((ext_vector_type(8)));
typedef unsigned short u16x4 __attribute__((ext_vector_type(4)));
typedef unsigned short u16x8 __attribute__((ext_vector_type(8)));

__device__ __forceinline__ unsigned short f2bf(float f) {
    unsigned u = __builtin_bit_cast(unsigned, f);
    u = (u + 0x7fffu + ((u >> 16) & 1u)) >> 16;
    return (unsigned short)u;
}

// ---------------------------------------------------------------------------
// Routing: one wave per token.
// ---------------------------------------------------------------------------
__global__ __launch_bounds__(64) void route_k(
    const float* __restrict__ x, const float* __restrict__ gw,
    const float* __restrict__ bias, int* __restrict__ tidx,
    float* __restrict__ tw)
{
    const int t = blockIdx.x;
    const int lane = threadIdx.x;
    __shared__ float xs[H_DIM];
    __shared__ float sfc[E_NUM];
    __shared__ float sc[E_NUM];

    for (int i = lane; i < H_DIM / 4; i += 64)
        *(f32x4*)&xs[i * 4] = *(const f32x4*)(x + (size_t)t * H_DIM + i * 4);
    __syncthreads();

    const int e = lane & 31;
    const int half = lane >> 5;
    float acc = 0.f;
    const float* gcol = gw + e;
    const int h0 = half * (H_DIM / 2);
    for (int h = h0; h < h0 + H_DIM / 2; ++h)
        acc += xs[h] * gcol[(size_t)h * E_NUM];
    acc += __shfl_xor(acc, 32);
    if (lane < 32) {
        float s = 1.f / (1.f + expf(-acc));
        sc[e] = s;
        sfc[e] = s + bias[e];
    }
    __syncthreads();

    if (lane == 0) {
        float gs[4];
        for (int gg = 0; gg < 4; ++gg) {
            float m1 = -1e30f, m2 = -1e30f;
            for (int j = 0; j < 8; ++j) {
                float v = sfc[gg * 8 + j];
                if (v > m1) { m2 = m1; m1 = v; }
                else if (v > m2) { m2 = v; }
            }
            gs[gg] = m1 + m2;
        }
        int g1 = 0;
        for (int gg = 1; gg < 4; ++gg) if (gs[gg] > gs[g1]) g1 = gg;
        int g2 = (g1 == 0) ? 1 : 0;
        for (int gg = 0; gg < 4; ++gg)
            if (gg != g1 && gs[gg] > gs[g2]) g2 = gg;

        unsigned allow = (0xFFu << (g1 * 8)) | (0xFFu << (g2 * 8));
        unsigned taken = 0u;
        int   isel[8];
        float wsel[8];
        float wsum = 0.f;
        for (int k = 0; k < 8; ++k) {
            int best = 0; float bv = -1e30f;
            for (int e2 = 0; e2 < 32; ++e2) {
                if (((allow >> e2) & 1u) && !((taken >> e2) & 1u)) {
                    float v = sfc[e2];
                    if (v > bv) { bv = v; best = e2; }
                }
            }
            taken |= 1u << best;
            isel[k] = best;
            wsel[k] = sc[best];
            wsum += sc[best];
        }
        const float f = 2.5f / wsum;
        for (int k = 0; k < 8; ++k) {
            tidx[t * 8 + k] = isel[k];
            tw[t * 8 + k] = wsel[k] * f;
        }
    }
}

// ---------------------------------------------------------------------------
// Build per-expert token lists (ascending token id). One wave per expert.
// ---------------------------------------------------------------------------
__global__ __launch_bounds__(64) void build_k(
    const int* __restrict__ tidx, const float* __restrict__ tw,
    int* __restrict__ ltok, float* __restrict__ lw, int* __restrict__ counts)
{
    const int e = blockIdx.x;
    const int lane = threadIdx.x;
    int cnt = 0;
    for (int t0 = 0; t0 < T_TOK; t0 += 64) {
        const int t = t0 + lane;
        int sel = 0; float w = 0.f;
        #pragma unroll
        for (int k = 0; k < 8; ++k) {
            if (tidx[t * 8 + k] == e) { sel = 1; w = tw[t * 8 + k]; }
        }
        unsigned long long m = __ballot(sel);
        int pos = __popcll(m & ((1ull << lane) - 1ull));
        if (sel) {
            ltok[e * T_TOK + cnt + pos] = t;
            lw[e * T_TOK + cnt + pos] = w;
        }
        cnt += __popcll(m);
    }
    if (lane == 0) counts[e] = cnt;
}

__global__ void prefix_k(const int* __restrict__ counts, int* __restrict__ offsets)
{
    if (threadIdx.x == 0) {
        int off = 0;
        for (int e = 0; e < E_NUM; ++e) { offsets[e] = off; off += counts[e]; }
    }
}

// ---------------------------------------------------------------------------
// GEMM: BMx64 tile, BK=32, 512 threads (8 waves, 4Mx2N), double-buffered LDS,
// DEPTH-2 register pipeline: loads for tile k+2 issued before compute(k), so
// the store of tile k+1's registers waits on a counted vmcnt (never drains).
// One barrier per K-tile.
// ---------------------------------------------------------------------------
template<int DUAL, int EXPERT, int ABF16, int ATOMIC, int BM>
__global__ __launch_bounds__(512) void gemm_k(
    const void* __restrict__ Av, const float* __restrict__ B1g,
    const float* __restrict__ B2g, void* __restrict__ outv,
    const int* __restrict__ counts, const int* __restrict__ offsets,
    const int* __restrict__ ltok, const float* __restrict__ lw,
    int M, int N, int K)
{
    constexpr int FM  = BM / 64;     // A frags per wave
    constexpr int WR  = BM / 4;      // rows per M-wave stripe
    constexpr int TPR = 512 / BM;    // threads per A row (2 or 4)
    constexpr int KSP = 32 / TPR;    // k elems per thread (16 or 8)
    constexpr int NL  = KSP / 4;     // f32x4 loads per A row chunk
    constexpr int NB  = (KSP + 7) / 8; // u16x8 ops per A row chunk

    const int e = blockIdx.z;
    int Mloc = EXPERT ? counts[e] : M;
    const int row0 = blockIdx.x * BM;
    if (row0 >= Mloc) return;
    const int col0 = blockIdx.y * 64;

    const float* B1 = B1g;
    const float* B2 = B2g;
    if (EXPERT) {
        size_t eo = (size_t)e * K * N;
        B1 += eo;
        if (DUAL) B2 += eo;
    }

    __shared__ unsigned short lA[2][BM][40];
    __shared__ unsigned short lB[2][DUAL + 1][64][40];

    const int tid = threadIdx.x;
    const int lane = tid & 63;
    const int wv = tid >> 6;
    const int wm = wv >> 1;          // 0..3
    const int wn = wv & 1;           // 0..1

    // ---- A staging: one row per thread, KSP contiguous k ----
    const int arow = tid / TPR;
    const int akb  = (tid % TPR) * KSP;
    const float* apf = nullptr;
    const unsigned short* apb = nullptr;
    {
        int rr = row0 + arow;
        if (rr >= Mloc) rr = Mloc - 1;
        if (ABF16) {
            const int rb = EXPERT ? offsets[e] : 0;
            apb = (const unsigned short*)Av + (size_t)(rb + rr) * K + akb;
        } else {
            int grow = EXPERT ? ltok[e * T_TOK + rr] : rr;
            apf = (const float*)Av + (size_t)grow * K + akb;
        }
    }

    // ---- B staging: 4k x 4n micro-tile per thread ----
    // DUAL: threads 0..255 (128 per matrix); single: threads 0..127
    const bool doB = tid < (DUAL ? 256 : 128);
    const int bmat = DUAL ? (tid >> 7) : 0;
    const int t7 = tid & 127;
    const int nq = t7 & 15;          // n group of 4
    const int kq = t7 >> 4;          // k group of 4 (0..7)
    const float* bp = (bmat ? B2 : B1) + (size_t)(4 * kq) * N + col0 + nq * 4;

    f32x4 acc1[FM][2], acc2[FM][2];
    #pragma unroll
    for (int a = 0; a < FM; ++a)
        #pragma unroll
        for (int b = 0; b < 2; ++b) {
            acc1[a][b] = f32x4{0.f, 0.f, 0.f, 0.f};
            acc2[a][b] = f32x4{0.f, 0.f, 0.f, 0.f};
        }

    // Two register batches (depth-2 pipeline), statically named.
    f32x4 paX[NL], paY[NL];
    u16x8 pbaX[NB], pbaY[NB];
    f32x4 pbX[4], pbY[4];

    auto loadT = [&](int k0, f32x4 (&pa)[NL], u16x8 (&pba)[NB], f32x4 (&pb)[4]) {
        if (ABF16) {
            #pragma unroll
            for (int i = 0; i < NB; ++i)
                pba[i] = *(const u16x8*)(apb + k0 + i * 8);
        } else {
            #pragma unroll
            for (int i = 0; i < NL; ++i)
                pa[i] = *(const f32x4*)(apf + k0 + i * 4);
        }
        if (doB) {
            #pragma unroll
            for (int j = 0; j < 4; ++j)
                pb[j] = *(const f32x4*)(bp + (size_t)(k0 + j) * N);
        }
    };

    auto storeT = [&](int p, f32x4 (&pa)[NL], u16x8 (&pba)[NB], f32x4 (&pb)[4]) {
        if (ABF16) {
            #pragma unroll
            for (int i = 0; i < NB; ++i)
                *(u16x8*)&lA[p][arow][akb + i * 8] = pba[i];
        } else {
            #pragma unroll
            for (int i = 0; i < NL; i += 2) {
                u16x8 h = { f2bf(pa[i][0]),   f2bf(pa[i][1]),
                            f2bf(pa[i][2]),   f2bf(pa[i][3]),
                            f2bf(pa[i+1][0]), f2bf(pa[i+1][1]),
                            f2bf(pa[i+1][2]), f2bf(pa[i+1][3]) };
                *(u16x8*)&lA[p][arow][akb + i * 4] = h;
            }
        }
        if (doB) {
            #pragma unroll
            for (int j2 = 0; j2 < 4; ++j2) {
                u16x4 h = { f2bf(pb[0][j2]), f2bf(pb[1][j2]),
                            f2bf(pb[2][j2]), f2bf(pb[3][j2]) };
                *(u16x4*)&lB[p][bmat][nq * 4 + j2][kq * 4] = h;
            }
        }
    };

    auto compute = [&](int p) {
        const int koff = (lane >> 4) * 8;
        s16x8 af[FM], b1f[2], b2f[2];
        #pragma unroll
        for (int fm = 0; fm < FM; ++fm)
            af[fm] = *(const s16x8*)&lA[p][wm * WR + fm * 16 + (lane & 15)][koff];
        #pragma unroll
        for (int fn = 0; fn < 2; ++fn) {
            b1f[fn] = *(const s16x8*)&lB[p][0][wn * 32 + fn * 16 + (lane & 15)][koff];
            if (DUAL)
                b2f[fn] = *(const s16x8*)&lB[p][1][wn * 32 + fn * 16 + (lane & 15)][koff];
        }
        #pragma unroll
        for (int fm = 0; fm < FM; ++fm)
            #pragma unroll
            for (int fn = 0; fn < 2; ++fn) {
                acc1[fm][fn] = __builtin_amdgcn_mfma_f32_16x16x32_bf16(
                    af[fm], b1f[fn], acc1[fm][fn], 0, 0, 0);
                if (DUAL)
                    acc2[fm][fn] = __builtin_amdgcn_mfma_f32_16x16x32_bf16(
                        af[fm], b2f[fn], acc2[fm][fn], 0, 0, 0);
            }
    };

    const int nk = K >> 5;           // 32, 64 — always even, >= 2
    loadT(0, paX, pbaX, pbX);
    loadT(32, paY, pbaY, pbY);
    storeT(0, paX, pbaX, pbX);
    __syncthreads();

    for (int kt = 0; kt < nk; kt += 2) {
        // even tile: lds[0]; setY holds tile kt+1 (in flight)
        if (kt + 2 < nk) loadT((kt + 2) << 5, paX, pbaX, pbX); // deepen pipe
        compute(0);
        storeT(1, paY, pbaY, pbY);   // counted wait: setX loads stay in flight
        __syncthreads();
        // odd tile: lds[1]; setX holds tile kt+2
        if (kt + 3 < nk) loadT((kt + 3) << 5, paY, pbaY, pbY);
        compute(1);
        if (kt + 2 < nk) {
            storeT(0, paX, pbaX, pbX);
            __syncthreads();
        }
    }

    // ---- epilogue ----
    const int fr = (lane >> 4) << 2;
    const int fc = lane & 15;
    if (DUAL) {
        unsigned short* outp = (unsigned short*)outv;
        const int rb = EXPERT ? offsets[e] : 0;
        #pragma unroll
        for (int fm = 0; fm < FM; ++fm)
            #pragma unroll
            for (int fn = 0; fn < 2; ++fn)
                #pragma unroll
                for (int j = 0; j < 4; ++j) {
                    int r = wm * WR + fm * 16 + fr + j;
                    if (row0 + r < Mloc) {
                        int cc = col0 + wn * 32 + fn * 16 + fc;
                        float gv = acc1[fm][fn][j];
                        float uv = acc2[fm][fn][j];
                        float a = gv / (1.f + expf(-gv)) * uv;
                        outp[(size_t)(rb + row0 + r) * N + cc] = f2bf(a);
                    }
                }
    } else if (ATOMIC) {
        float* outp = (float*)outv;
        #pragma unroll
        for (int fm = 0; fm < FM; ++fm)
            #pragma unroll
            for (int fn = 0; fn < 2; ++fn)
                #pragma unroll
                for (int j = 0; j < 4; ++j) {
                    int r = wm * WR + fm * 16 + fr + j;
                    if (row0 + r < Mloc) {
                        int tok = ltok[e * T_TOK + row0 + r];
                        float wr = lw[e * T_TOK + row0 + r];
                        int cc = col0 + wn * 32 + fn * 16 + fc;
                        atomicAdd(outp + (size_t)tok * N + cc, acc1[fm][fn][j] * wr);
                    }
                }
    } else {
        float* outp = (float*)outv;
        #pragma unroll
        for (int fm = 0; fm < FM; ++fm)
            #pragma unroll
            for (int fn = 0; fn < 2; ++fn)
                #pragma unroll
                for (int j = 0; j < 4; ++j) {
                    int r = wm * WR + fm * 16 + fr + j;
                    if (row0 + r < Mloc) {
                        int cc = col0 + wn * 32 + fn * 16 + fc;
                        outp[(size_t)(row0 + r) * N + cc] = acc1[fm][fn][j];
                    }
                }
    }
}

// ---------------------------------------------------------------------------
extern "C" void kernel_launch(void* const* d_in, const int* in_sizes, int n_in,
                              void* d_out, int out_size, void* d_ws, size_t ws_size,
                              hipStream_t stream) {
    const float* x       = (const float*)d_in[0];
    const float* gate_w  = (const float*)d_in[1];
    const float* bias    = (const float*)d_in[2];
    const float* w_gate  = (const float*)d_in[3];
    const float* w_up    = (const float*)d_in[4];
    const float* w_down  = (const float*)d_in[5];
    const float* sw_gate = (const float*)d_in[6];
    const float* sw_up   = (const float*)d_in[7];
    const float* sw_down = (const float*)d_in[8];
    float* out = (float*)d_out;

    char* ws = (char*)d_ws;
    int*   topk_idx = (int*)ws;                                   // 32 KB
    float* topk_w   = (float*)(ws + 32768);                       // 32 KB
    int*   counts   = (int*)(ws + 65536);                         // 128 B
    int*   offsets  = (int*)(ws + 65536 + 128);                   // 128 B
    int*   ltok     = (int*)(ws + 65536 + 256);                   // 128 KB
    float* lw       = (float*)(ws + 65536 + 256 + 131072);        // 128 KB
    unsigned short* act_s = (unsigned short*)(ws + 65536 + 256 + 262144);  // 4 MB
    unsigned short* act_r = act_s + (size_t)T_TOK * IS_DIM;               // 16 MB

    route_k<<<T_TOK, 64, 0, stream>>>(x, gate_w, bias, topk_idx, topk_w);
    build_k<<<E_NUM, 64, 0, stream>>>(topk_idx, topk_w, ltok, lw, counts);
    prefix_k<<<1, 64, 0, stream>>>(counts, offsets);

    // shared gate/up -> act_s (bf16): BM=128
    gemm_k<1,0,0,0,128><<<dim3(8, 32, 1), 512, 0, stream>>>(
        x, sw_gate, sw_up, act_s, nullptr, nullptr, nullptr, nullptr,
        T_TOK, IS_DIM, H_DIM);
    // routed gate/up -> act_r (bf16): BM=256, weight panels read once
    gemm_k<1,1,0,0,256><<<dim3(4, 16, 32), 512, 0, stream>>>(
        x, w_gate, w_up, act_r, counts, offsets, ltok, lw,
        T_TOK, I_DIM, H_DIM);
    // shared down -> out (plain store, initializes out): BM=128
    gemm_k<0,0,1,0,128><<<dim3(8, 32, 1), 512, 0, stream>>>(
        act_s, sw_down, nullptr, out, nullptr, nullptr, nullptr, nullptr,
        T_TOK, H_DIM, IS_DIM);
    // routed down -> out (scaled atomicAdd): BM=256
    gemm_k<0,1,1,1,256><<<dim3(4, 32, 32), 512, 0, stream>>>(
        act_r, w_down, nullptr, out, counts, offsets, ltok, lw,
        T_TOK, H_DIM, I_DIM);
}

// Round 5
// 1023.215 us; speedup vs baseline: 1.5119x; 1.5119x over previous
//
#include <hip/hip_runtime.h>

// Sizes (fixed for this problem)
#define T_TOK 1024
#define H_DIM 2048
#define E_NUM 32
#define I_DIM 1024
#define IS_DIM 2048

typedef float  f32x4 __attribute__((ext_vector_type(4)));
typedef short  s16x8 __attribute__((ext_vector_type(8)));
typedef unsigned short u16x4 __attribute__((ext_vector_type(4)));
typedef unsigned short u16x8 __attribute__((ext_vector_type(8)));

__device__ __forceinline__ unsigned short f2bf(float f) {
    unsigned u = __builtin_bit_cast(unsigned, f);
    u = (u + 0x7fffu + ((u >> 16) & 1u)) >> 16;
    return (unsigned short)u;
}

// LDS column swizzle: rows are 32 u16 (64 B); XOR col-block (8 u16) with
// bits of the row so strided row access spreads across banks. Keeps 16 B
// alignment for 8-aligned columns.
__device__ __forceinline__ int swz(int r, int c) {
    return (r << 5) + (c ^ (((r >> 2) & 3) << 3));
}

// ---------------------------------------------------------------------------
// Routing: one wave per token.
// ---------------------------------------------------------------------------
__global__ __launch_bounds__(64) void route_k(
    const float* __restrict__ x, const float* __restrict__ gw,
    const float* __restrict__ bias, int* __restrict__ tidx,
    float* __restrict__ tw)
{
    const int t = blockIdx.x;
    const int lane = threadIdx.x;
    __shared__ float xs[H_DIM];
    __shared__ float sfc[E_NUM];
    __shared__ float sc[E_NUM];

    for (int i = lane; i < H_DIM / 4; i += 64)
        *(f32x4*)&xs[i * 4] = *(const f32x4*)(x + (size_t)t * H_DIM + i * 4);
    __syncthreads();

    const int e = lane & 31;
    const int half = lane >> 5;
    float acc = 0.f;
    const float* gcol = gw + e;
    const int h0 = half * (H_DIM / 2);
    for (int h = h0; h < h0 + H_DIM / 2; ++h)
        acc += xs[h] * gcol[(size_t)h * E_NUM];
    acc += __shfl_xor(acc, 32);
    if (lane < 32) {
        float s = 1.f / (1.f + expf(-acc));
        sc[e] = s;
        sfc[e] = s + bias[e];
    }
    __syncthreads();

    if (lane == 0) {
        float gs[4];
        for (int gg = 0; gg < 4; ++gg) {
            float m1 = -1e30f, m2 = -1e30f;
            for (int j = 0; j < 8; ++j) {
                float v = sfc[gg * 8 + j];
                if (v > m1) { m2 = m1; m1 = v; }
                else if (v > m2) { m2 = v; }
            }
            gs[gg] = m1 + m2;
        }
        int g1 = 0;
        for (int gg = 1; gg < 4; ++gg) if (gs[gg] > gs[g1]) g1 = gg;
        int g2 = (g1 == 0) ? 1 : 0;
        for (int gg = 0; gg < 4; ++gg)
            if (gg != g1 && gs[gg] > gs[g2]) g2 = gg;

        unsigned allow = (0xFFu << (g1 * 8)) | (0xFFu << (g2 * 8));
        unsigned taken = 0u;
        int   isel[8];
        float wsel[8];
        float wsum = 0.f;
        for (int k = 0; k < 8; ++k) {
            int best = 0; float bv = -1e30f;
            for (int e2 = 0; e2 < 32; ++e2) {
                if (((allow >> e2) & 1u) && !((taken >> e2) & 1u)) {
                    float v = sfc[e2];
                    if (v > bv) { bv = v; best = e2; }
                }
            }
            taken |= 1u << best;
            isel[k] = best;
            wsel[k] = sc[best];
            wsum += sc[best];
        }
        const float f = 2.5f / wsum;
        for (int k = 0; k < 8; ++k) {
            tidx[t * 8 + k] = isel[k];
            tw[t * 8 + k] = wsel[k] * f;
        }
    }
}

// ---------------------------------------------------------------------------
// Build per-expert token lists (ascending token id). One wave per expert.
// ---------------------------------------------------------------------------
__global__ __launch_bounds__(64) void build_k(
    const int* __restrict__ tidx, const float* __restrict__ tw,
    int* __restrict__ ltok, float* __restrict__ lw, int* __restrict__ counts)
{
    const int e = blockIdx.x;
    const int lane = threadIdx.x;
    int cnt = 0;
    for (int t0 = 0; t0 < T_TOK; t0 += 64) {
        const int t = t0 + lane;
        int sel = 0; float w = 0.f;
        #pragma unroll
        for (int k = 0; k < 8; ++k) {
            if (tidx[t * 8 + k] == e) { sel = 1; w = tw[t * 8 + k]; }
        }
        unsigned long long m = __ballot(sel);
        int pos = __popcll(m & ((1ull << lane) - 1ull));
        if (sel) {
            ltok[e * T_TOK + cnt + pos] = t;
            lw[e * T_TOK + cnt + pos] = w;
        }
        cnt += __popcll(m);
    }
    if (lane == 0) counts[e] = cnt;
}

__global__ void prefix_k(const int* __restrict__ counts, int* __restrict__ offsets)
{
    if (threadIdx.x == 0) {
        int off = 0;
        for (int e = 0; e < E_NUM; ++e) { offsets[e] = off; off += counts[e]; }
    }
}

// ---------------------------------------------------------------------------
// GEMM: BMx64 tile, BK=32, 512 threads (8 waves, 4Mx2N), double-buffered LDS
// (XOR-swizzled), depth-2 register pipeline, in-block loop over M tiles
// (grid.x may be 1: block strides row0 by gridDim.x*BM -> no no-op blocks).
// ---------------------------------------------------------------------------
template<int DUAL, int EXPERT, int ABF16, int ATOMIC, int BM>
__global__ __launch_bounds__(512) void gemm_k(
    const void* __restrict__ Av, const float* __restrict__ B1g,
    const float* __restrict__ B2g, void* __restrict__ outv,
    const int* __restrict__ counts, const int* __restrict__ offsets,
    const int* __restrict__ ltok, const float* __restrict__ lw,
    int M, int N, int K)
{
    constexpr int FM  = BM / 64;       // A frags per wave
    constexpr int WR  = BM / 4;        // rows per M-wave stripe
    constexpr int TPR = 512 / BM;      // threads per A row (2 or 4)
    constexpr int KSP = 32 / TPR;      // k elems per thread (16 or 8)
    constexpr int NL  = KSP / 4;       // f32x4 loads per A row chunk
    constexpr int NB  = KSP / 8;       // u16x8 ops per A row chunk

    const int e = blockIdx.z;
    const int Mloc = EXPERT ? counts[e] : M;
    const int col0 = blockIdx.y * 64;
    const int rb = EXPERT ? offsets[e] : 0;

    const float* B1 = B1g;
    const float* B2 = B2g;
    if (EXPERT) {
        size_t eo = (size_t)e * K * N;
        B1 += eo;
        if (DUAL) B2 += eo;
    }

    __shared__ unsigned short lA[2][BM * 32];
    __shared__ unsigned short lB[2][DUAL + 1][64 * 32];

    const int tid = threadIdx.x;
    const int lane = tid & 63;
    const int wv = tid >> 6;
    const int wm = wv >> 1;            // 0..3
    const int wn = wv & 1;             // 0..1

    const int arow = tid / TPR;
    const int akb  = (tid % TPR) * KSP;

    // ---- B staging: 4k x 4n micro-tile per thread ----
    const bool doB = tid < (DUAL ? 256 : 128);
    const int bmat = DUAL ? (tid >> 7) : 0;
    const int t7 = tid & 127;
    const int nq = t7 & 15;            // n group of 4
    const int kq = t7 >> 4;            // k group of 4 (0..7)
    const float* bp = (bmat ? B2 : B1) + (size_t)(4 * kq) * N + col0 + nq * 4;

    f32x4 acc1[FM][2], acc2[FM][2];
    f32x4 paX[NL], paY[NL];
    u16x8 pbaX[NB], pbaY[NB];
    f32x4 pbX[4], pbY[4];

    const float* apf = nullptr;
    const unsigned short* apb = nullptr;

    auto loadT = [&](int k0, f32x4 (&pa)[NL], u16x8 (&pba)[NB], f32x4 (&pb)[4]) {
        if (ABF16) {
            #pragma unroll
            for (int i = 0; i < NB; ++i)
                pba[i] = *(const u16x8*)(apb + k0 + i * 8);
        } else {
            #pragma unroll
            for (int i = 0; i < NL; ++i)
                pa[i] = *(const f32x4*)(apf + k0 + i * 4);
        }
        if (doB) {
            #pragma unroll
            for (int j = 0; j < 4; ++j)
                pb[j] = *(const f32x4*)(bp + (size_t)(k0 + j) * N);
        }
    };

    auto storeT = [&](int p, f32x4 (&pa)[NL], u16x8 (&pba)[NB], f32x4 (&pb)[4]) {
        if (ABF16) {
            #pragma unroll
            for (int i = 0; i < NB; ++i)
                *(u16x8*)&lA[p][swz(arow, akb + i * 8)] = pba[i];
        } else {
            #pragma unroll
            for (int i = 0; i < NL; i += 2) {
                u16x8 h = { f2bf(pa[i][0]),   f2bf(pa[i][1]),
                            f2bf(pa[i][2]),   f2bf(pa[i][3]),
                            f2bf(pa[i+1][0]), f2bf(pa[i+1][1]),
                            f2bf(pa[i+1][2]), f2bf(pa[i+1][3]) };
                *(u16x8*)&lA[p][swz(arow, akb + i * 4)] = h;
            }
        }
        if (doB) {
            #pragma unroll
            for (int j2 = 0; j2 < 4; ++j2) {
                u16x4 h = { f2bf(pb[0][j2]), f2bf(pb[1][j2]),
                            f2bf(pb[2][j2]), f2bf(pb[3][j2]) };
                *(u16x4*)&lB[p][bmat][swz(nq * 4 + j2, kq * 4)] = h;
            }
        }
    };

    auto compute = [&](int p) {
        const int koff = (lane >> 4) * 8;
        s16x8 af[FM], b1f[2], b2f[2];
        #pragma unroll
        for (int fm = 0; fm < FM; ++fm)
            af[fm] = *(const s16x8*)&lA[p][swz(wm * WR + fm * 16 + (lane & 15), koff)];
        #pragma unroll
        for (int fn = 0; fn < 2; ++fn) {
            b1f[fn] = *(const s16x8*)&lB[p][0][swz(wn * 32 + fn * 16 + (lane & 15), koff)];
            if (DUAL)
                b2f[fn] = *(const s16x8*)&lB[p][1][swz(wn * 32 + fn * 16 + (lane & 15), koff)];
        }
        #pragma unroll
        for (int fm = 0; fm < FM; ++fm)
            #pragma unroll
            for (int fn = 0; fn < 2; ++fn) {
                acc1[fm][fn] = __builtin_amdgcn_mfma_f32_16x16x32_bf16(
                    af[fm], b1f[fn], acc1[fm][fn], 0, 0, 0);
                if (DUAL)
                    acc2[fm][fn] = __builtin_amdgcn_mfma_f32_16x16x32_bf16(
                        af[fm], b2f[fn], acc2[fm][fn], 0, 0, 0);
            }
    };

    const int nk = K >> 5;             // >= 32, even

    for (int row0 = blockIdx.x * BM; row0 < Mloc; row0 += gridDim.x * BM) {
        // ---- A pointers for this m-tile ----
        {
            int rr = row0 + arow;
            if (rr >= Mloc) rr = Mloc - 1;
            if (ABF16) {
                apb = (const unsigned short*)Av + (size_t)(rb + rr) * K + akb;
            } else {
                int grow = EXPERT ? ltok[e * T_TOK + rr] : rr;
                apf = (const float*)Av + (size_t)grow * K + akb;
            }
        }
        #pragma unroll
        for (int a = 0; a < FM; ++a)
            #pragma unroll
            for (int b = 0; b < 2; ++b) {
                acc1[a][b] = f32x4{0.f, 0.f, 0.f, 0.f};
                acc2[a][b] = f32x4{0.f, 0.f, 0.f, 0.f};
            }

        loadT(0, paX, pbaX, pbX);
        loadT(32, paY, pbaY, pbY);
        __syncthreads();               // prior m-tile's compute fully done
        storeT(0, paX, pbaX, pbX);
        __syncthreads();

        for (int kt = 0; kt < nk; kt += 2) {
            if (kt + 2 < nk) loadT((kt + 2) << 5, paX, pbaX, pbX);
            compute(0);
            storeT(1, paY, pbaY, pbY);   // counted vmcnt: newer loads in flight
            __syncthreads();
            if (kt + 3 < nk) loadT((kt + 3) << 5, paY, pbaY, pbY);
            compute(1);
            if (kt + 2 < nk) {
                storeT(0, paX, pbaX, pbX);
                __syncthreads();
            }
        }

        // ---- epilogue ----
        const int fr = (lane >> 4) << 2;
        const int fc = lane & 15;
        if (DUAL) {
            unsigned short* outp = (unsigned short*)outv;
            #pragma unroll
            for (int fm = 0; fm < FM; ++fm)
                #pragma unroll
                for (int fn = 0; fn < 2; ++fn)
                    #pragma unroll
                    for (int j = 0; j < 4; ++j) {
                        int r = wm * WR + fm * 16 + fr + j;
                        if (row0 + r < Mloc) {
                            int cc = col0 + wn * 32 + fn * 16 + fc;
                            float gv = acc1[fm][fn][j];
                            float uv = acc2[fm][fn][j];
                            float a = gv / (1.f + expf(-gv)) * uv;
                            outp[(size_t)(rb + row0 + r) * N + cc] = f2bf(a);
                        }
                    }
        } else if (ATOMIC) {
            float* outp = (float*)outv;
            #pragma unroll
            for (int fm = 0; fm < FM; ++fm)
                #pragma unroll
                for (int fn = 0; fn < 2; ++fn)
                    #pragma unroll
                    for (int j = 0; j < 4; ++j) {
                        int r = wm * WR + fm * 16 + fr + j;
                        if (row0 + r < Mloc) {
                            int tok = ltok[e * T_TOK + row0 + r];
                            float wr = lw[e * T_TOK + row0 + r];
                            int cc = col0 + wn * 32 + fn * 16 + fc;
                            atomicAdd(outp + (size_t)tok * N + cc, acc1[fm][fn][j] * wr);
                        }
                    }
        } else {
            float* outp = (float*)outv;
            #pragma unroll
            for (int fm = 0; fm < FM; ++fm)
                #pragma unroll
                for (int fn = 0; fn < 2; ++fn)
                    #pragma unroll
                    for (int j = 0; j < 4; ++j) {
                        int r = wm * WR + fm * 16 + fr + j;
                        if (row0 + r < Mloc) {
                            int cc = col0 + wn * 32 + fn * 16 + fc;
                            outp[(size_t)(row0 + r) * N + cc] = acc1[fm][fn][j];
                        }
                    }
        }
    }
}

// ---------------------------------------------------------------------------
extern "C" void kernel_launch(void* const* d_in, const int* in_sizes, int n_in,
                              void* d_out, int out_size, void* d_ws, size_t ws_size,
                              hipStream_t stream) {
    const float* x       = (const float*)d_in[0];
    const float* gate_w  = (const float*)d_in[1];
    const float* bias    = (const float*)d_in[2];
    const float* w_gate  = (const float*)d_in[3];
    const float* w_up    = (const float*)d_in[4];
    const float* w_down  = (const float*)d_in[5];
    const float* sw_gate = (const float*)d_in[6];
    const float* sw_up   = (const float*)d_in[7];
    const float* sw_down = (const float*)d_in[8];
    float* out = (float*)d_out;

    char* ws = (char*)d_ws;
    int*   topk_idx = (int*)ws;                                   // 32 KB
    float* topk_w   = (float*)(ws + 32768);                       // 32 KB
    int*   counts   = (int*)(ws + 65536);                         // 128 B
    int*   offsets  = (int*)(ws + 65536 + 128);                   // 128 B
    int*   ltok     = (int*)(ws + 65536 + 256);                   // 128 KB
    float* lw       = (float*)(ws + 65536 + 256 + 131072);        // 128 KB
    unsigned short* act_s = (unsigned short*)(ws + 65536 + 256 + 262144);  // 4 MB
    unsigned short* act_r = act_s + (size_t)T_TOK * IS_DIM;               // 16 MB

    route_k<<<T_TOK, 64, 0, stream>>>(x, gate_w, bias, topk_idx, topk_w);
    build_k<<<E_NUM, 64, 0, stream>>>(topk_idx, topk_w, ltok, lw, counts);
    prefix_k<<<1, 64, 0, stream>>>(counts, offsets);

    // shared gate/up -> act_s (bf16): BM=128, all 256 blocks work
    gemm_k<1,0,0,0,128><<<dim3(8, 32, 1), 512, 0, stream>>>(
        x, sw_gate, sw_up, act_s, nullptr, nullptr, nullptr, nullptr,
        T_TOK, IS_DIM, H_DIM);
    // routed gate/up -> act_r (bf16): BM=256, exact grid + in-block m-loop
    gemm_k<1,1,0,0,256><<<dim3(1, 16, 32), 512, 0, stream>>>(
        x, w_gate, w_up, act_r, counts, offsets, ltok, lw,
        T_TOK, I_DIM, H_DIM);
    // shared down -> out (plain store, initializes out): BM=128
    gemm_k<0,0,1,0,128><<<dim3(8, 32, 1), 512, 0, stream>>>(
        act_s, sw_down, nullptr, out, nullptr, nullptr, nullptr, nullptr,
        T_TOK, H_DIM, IS_DIM);
    // routed down -> out (scaled atomicAdd): BM=256, exact grid
    gemm_k<0,1,1,1,256><<<dim3(1, 32, 32), 512, 0, stream>>>(
        act_r, w_down, nullptr, out, counts, offsets, ltok, lw,
        T_TOK, H_DIM, I_DIM);
}

// Round 6
// 716.029 us; speedup vs baseline: 2.1606x; 1.4290x over previous
//
#include <hip/hip_runtime.h>

// Sizes (fixed for this problem)
#define T_TOK 1024
#define H_DIM 2048
#define E_NUM 32
#define I_DIM 1024
#define IS_DIM 2048

typedef float  f32x4 __attribute__((ext_vector_type(4)));
typedef short  s16x8 __attribute__((ext_vector_type(8)));
typedef unsigned short u16x4 __attribute__((ext_vector_type(4)));
typedef unsigned short u16x8 __attribute__((ext_vector_type(8)));

__device__ __forceinline__ unsigned short f2bf(float f) {
    unsigned u = __builtin_bit_cast(unsigned, f);
    u = (u + 0x7fffu + ((u >> 16) & 1u)) >> 16;
    return (unsigned short)u;
}

// LDS column swizzle: rows are 32 u16 (64 B); XOR col-block (8 u16) with
// bits of the row so strided row access spreads across banks. Keeps 16 B
// alignment for 8-aligned columns.
__device__ __forceinline__ int swz(int r, int c) {
    return (r << 5) + (c ^ (((r >> 2) & 3) << 3));
}

// ---------------------------------------------------------------------------
// Routing: 4 tokens per 256-thread block, one wave per token.
// Lane l owns expert quad (l&7)*4 and h-offset l>>3 (stride 8):
// inner loop is f32x4 coalesced gate_w loads + 4 independent FMA chains.
// ---------------------------------------------------------------------------
__global__ __launch_bounds__(256) void route_k(
    const float* __restrict__ x, const float* __restrict__ gw,
    const float* __restrict__ bias, int* __restrict__ tidx,
    float* __restrict__ tw)
{
    const int w = threadIdx.x >> 6;        // wave -> local token
    const int lane = threadIdx.x & 63;
    const int t = blockIdx.x * 4 + w;
    __shared__ float xs[4][H_DIM];
    __shared__ float sfc[4][E_NUM];
    __shared__ float sc[4][E_NUM];

    // stage 4 token rows cooperatively
    for (int i = threadIdx.x; i < 4 * (H_DIM / 4); i += 256) {
        int tt = i >> 9;                   // i / 512
        int c = i & 511;                   // f32x4 index within row
        *(f32x4*)&xs[tt][c * 4] =
            *(const f32x4*)(x + (size_t)(blockIdx.x * 4 + tt) * H_DIM + c * 4);
    }
    __syncthreads();

    const int eq = (lane & 7) * 4;         // expert quad base
    const int hs = lane >> 3;              // h offset 0..7
    f32x4 acc = {0.f, 0.f, 0.f, 0.f};
    #pragma unroll 4
    for (int h = hs; h < H_DIM; h += 8) {
        float xv = xs[w][h];
        f32x4 gv = *(const f32x4*)(gw + (size_t)h * E_NUM + eq);
        acc += gv * xv;
    }
    // reduce across the 8 h-groups (lane bits 3..5)
    #pragma unroll
    for (int m = 8; m < 64; m <<= 1) {
        acc[0] += __shfl_xor(acc[0], m);
        acc[1] += __shfl_xor(acc[1], m);
        acc[2] += __shfl_xor(acc[2], m);
        acc[3] += __shfl_xor(acc[3], m);
    }
    if (lane < 8) {
        #pragma unroll
        for (int j = 0; j < 4; ++j) {
            float s = 1.f / (1.f + expf(-acc[j]));
            sc[w][eq + j] = s;
            sfc[w][eq + j] = s + bias[eq + j];
        }
    }
    __syncthreads();

    if (lane == 0) {
        float gs[4];
        for (int gg = 0; gg < 4; ++gg) {
            float m1 = -1e30f, m2 = -1e30f;
            for (int j = 0; j < 8; ++j) {
                float v = sfc[w][gg * 8 + j];
                if (v > m1) { m2 = m1; m1 = v; }
                else if (v > m2) { m2 = v; }
            }
            gs[gg] = m1 + m2;
        }
        int g1 = 0;
        for (int gg = 1; gg < 4; ++gg) if (gs[gg] > gs[g1]) g1 = gg;
        int g2 = (g1 == 0) ? 1 : 0;
        for (int gg = 0; gg < 4; ++gg)
            if (gg != g1 && gs[gg] > gs[g2]) g2 = gg;

        unsigned allow = (0xFFu << (g1 * 8)) | (0xFFu << (g2 * 8));
        unsigned taken = 0u;
        int   isel[8];
        float wsel[8];
        float wsum = 0.f;
        for (int k = 0; k < 8; ++k) {
            int best = 0; float bv = -1e30f;
            for (int e2 = 0; e2 < 32; ++e2) {
                if (((allow >> e2) & 1u) && !((taken >> e2) & 1u)) {
                    float v = sfc[w][e2];
                    if (v > bv) { bv = v; best = e2; }
                }
            }
            taken |= 1u << best;
            isel[k] = best;
            wsel[k] = sc[w][best];
            wsum += sc[w][best];
        }
        const float f = 2.5f / wsum;
        for (int k = 0; k < 8; ++k) {
            tidx[t * 8 + k] = isel[k];
            tw[t * 8 + k] = wsel[k] * f;
        }
    }
}

// ---------------------------------------------------------------------------
// Build per-expert token lists (ascending token id). One wave per expert.
// ---------------------------------------------------------------------------
__global__ __launch_bounds__(64) void build_k(
    const int* __restrict__ tidx, const float* __restrict__ tw,
    int* __restrict__ ltok, float* __restrict__ lw, int* __restrict__ counts)
{
    const int e = blockIdx.x;
    const int lane = threadIdx.x;
    int cnt = 0;
    for (int t0 = 0; t0 < T_TOK; t0 += 64) {
        const int t = t0 + lane;
        int sel = 0; float w = 0.f;
        #pragma unroll
        for (int k = 0; k < 8; ++k) {
            if (tidx[t * 8 + k] == e) { sel = 1; w = tw[t * 8 + k]; }
        }
        unsigned long long m = __ballot(sel);
        int pos = __popcll(m & ((1ull << lane) - 1ull));
        if (sel) {
            ltok[e * T_TOK + cnt + pos] = t;
            lw[e * T_TOK + cnt + pos] = w;
        }
        cnt += __popcll(m);
    }
    if (lane == 0) counts[e] = cnt;
}

__global__ void prefix_k(const int* __restrict__ counts, int* __restrict__ offsets)
{
    if (threadIdx.x == 0) {
        int off = 0;
        for (int e = 0; e < E_NUM; ++e) { offsets[e] = off; off += counts[e]; }
    }
}

// ---------------------------------------------------------------------------
// GEMM: BMx64 tile, BK=32, 512 threads (8 waves, 4Mx2N), double-buffered LDS
// (XOR-swizzled), depth-2 register pipeline, in-block loop over M tiles
// (grid.x may be 1: block strides row0 by gridDim.x*BM -> no no-op blocks).
// ---------------------------------------------------------------------------
template<int DUAL, int EXPERT, int ABF16, int ATOMIC, int BM>
__global__ __launch_bounds__(512) void gemm_k(
    const void* __restrict__ Av, const float* __restrict__ B1g,
    const float* __restrict__ B2g, void* __restrict__ outv,
    const int* __restrict__ counts, const int* __restrict__ offsets,
    const int* __restrict__ ltok, const float* __restrict__ lw,
    int M, int N, int K)
{
    constexpr int FM  = BM / 64;       // A frags per wave
    constexpr int WR  = BM / 4;        // rows per M-wave stripe
    constexpr int TPR = 512 / BM;      // threads per A row (2 or 4)
    constexpr int KSP = 32 / TPR;      // k elems per thread (16 or 8)
    constexpr int NL  = KSP / 4;       // f32x4 loads per A row chunk
    constexpr int NB  = KSP / 8;       // u16x8 ops per A row chunk

    const int e = blockIdx.z;
    const int Mloc = EXPERT ? counts[e] : M;
    const int col0 = blockIdx.y * 64;
    const int rb = EXPERT ? offsets[e] : 0;

    const float* B1 = B1g;
    const float* B2 = B2g;
    if (EXPERT) {
        size_t eo = (size_t)e * K * N;
        B1 += eo;
        if (DUAL) B2 += eo;
    }

    __shared__ unsigned short lA[2][BM * 32];
    __shared__ unsigned short lB[2][DUAL + 1][64 * 32];

    const int tid = threadIdx.x;
    const int lane = tid & 63;
    const int wv = tid >> 6;
    const int wm = wv >> 1;            // 0..3
    const int wn = wv & 1;             // 0..1

    const int arow = tid / TPR;
    const int akb  = (tid % TPR) * KSP;

    // ---- B staging: 4k x 4n micro-tile per thread ----
    const bool doB = tid < (DUAL ? 256 : 128);
    const int bmat = DUAL ? (tid >> 7) : 0;
    const int t7 = tid & 127;
    const int nq = t7 & 15;            // n group of 4
    const int kq = t7 >> 4;            // k group of 4 (0..7)
    const float* bp = (bmat ? B2 : B1) + (size_t)(4 * kq) * N + col0 + nq * 4;

    f32x4 acc1[FM][2], acc2[FM][2];
    f32x4 paX[NL], paY[NL];
    u16x8 pbaX[NB], pbaY[NB];
    f32x4 pbX[4], pbY[4];

    const float* apf = nullptr;
    const unsigned short* apb = nullptr;

    auto loadT = [&](int k0, f32x4 (&pa)[NL], u16x8 (&pba)[NB], f32x4 (&pb)[4]) {
        if (ABF16) {
            #pragma unroll
            for (int i = 0; i < NB; ++i)
                pba[i] = *(const u16x8*)(apb + k0 + i * 8);
        } else {
            #pragma unroll
            for (int i = 0; i < NL; ++i)
                pa[i] = *(const f32x4*)(apf + k0 + i * 4);
        }
        if (doB) {
            #pragma unroll
            for (int j = 0; j < 4; ++j)
                pb[j] = *(const f32x4*)(bp + (size_t)(k0 + j) * N);
        }
    };

    auto storeT = [&](int p, f32x4 (&pa)[NL], u16x8 (&pba)[NB], f32x4 (&pb)[4]) {
        if (ABF16) {
            #pragma unroll
            for (int i = 0; i < NB; ++i)
                *(u16x8*)&lA[p][swz(arow, akb + i * 8)] = pba[i];
        } else {
            #pragma unroll
            for (int i = 0; i < NL; i += 2) {
                u16x8 h = { f2bf(pa[i][0]),   f2bf(pa[i][1]),
                            f2bf(pa[i][2]),   f2bf(pa[i][3]),
                            f2bf(pa[i+1][0]), f2bf(pa[i+1][1]),
                            f2bf(pa[i+1][2]), f2bf(pa[i+1][3]) };
                *(u16x8*)&lA[p][swz(arow, akb + i * 4)] = h;
            }
        }
        if (doB) {
            #pragma unroll
            for (int j2 = 0; j2 < 4; ++j2) {
                u16x4 h = { f2bf(pb[0][j2]), f2bf(pb[1][j2]),
                            f2bf(pb[2][j2]), f2bf(pb[3][j2]) };
                *(u16x4*)&lB[p][bmat][swz(nq * 4 + j2, kq * 4)] = h;
            }
        }
    };

    auto compute = [&](int p) {
        const int koff = (lane >> 4) * 8;
        s16x8 af[FM], b1f[2], b2f[2];
        #pragma unroll
        for (int fm = 0; fm < FM; ++fm)
            af[fm] = *(const s16x8*)&lA[p][swz(wm * WR + fm * 16 + (lane & 15), koff)];
        #pragma unroll
        for (int fn = 0; fn < 2; ++fn) {
            b1f[fn] = *(const s16x8*)&lB[p][0][swz(wn * 32 + fn * 16 + (lane & 15), koff)];
            if (DUAL)
                b2f[fn] = *(const s16x8*)&lB[p][1][swz(wn * 32 + fn * 16 + (lane & 15), koff)];
        }
        #pragma unroll
        for (int fm = 0; fm < FM; ++fm)
            #pragma unroll
            for (int fn = 0; fn < 2; ++fn) {
                acc1[fm][fn] = __builtin_amdgcn_mfma_f32_16x16x32_bf16(
                    af[fm], b1f[fn], acc1[fm][fn], 0, 0, 0);
                if (DUAL)
                    acc2[fm][fn] = __builtin_amdgcn_mfma_f32_16x16x32_bf16(
                        af[fm], b2f[fn], acc2[fm][fn], 0, 0, 0);
            }
    };

    const int nk = K >> 5;             // >= 32, even

    for (int row0 = blockIdx.x * BM; row0 < Mloc; row0 += gridDim.x * BM) {
        // ---- A pointers for this m-tile ----
        {
            int rr = row0 + arow;
            if (rr >= Mloc) rr = Mloc - 1;
            if (ABF16) {
                apb = (const unsigned short*)Av + (size_t)(rb + rr) * K + akb;
            } else {
                int grow = EXPERT ? ltok[e * T_TOK + rr] : rr;
                apf = (const float*)Av + (size_t)grow * K + akb;
            }
        }
        #pragma unroll
        for (int a = 0; a < FM; ++a)
            #pragma unroll
            for (int b = 0; b < 2; ++b) {
                acc1[a][b] = f32x4{0.f, 0.f, 0.f, 0.f};
                acc2[a][b] = f32x4{0.f, 0.f, 0.f, 0.f};
            }

        loadT(0, paX, pbaX, pbX);
        loadT(32, paY, pbaY, pbY);
        __syncthreads();               // prior m-tile's compute fully done
        storeT(0, paX, pbaX, pbX);
        __syncthreads();

        for (int kt = 0; kt < nk; kt += 2) {
            if (kt + 2 < nk) loadT((kt + 2) << 5, paX, pbaX, pbX);
            compute(0);
            storeT(1, paY, pbaY, pbY);   // counted vmcnt: newer loads in flight
            __syncthreads();
            if (kt + 3 < nk) loadT((kt + 3) << 5, paY, pbaY, pbY);
            compute(1);
            if (kt + 2 < nk) {
                storeT(0, paX, pbaX, pbX);
                __syncthreads();
            }
        }

        // ---- epilogue ----
        const int fr = (lane >> 4) << 2;
        const int fc = lane & 15;
        if (DUAL) {
            unsigned short* outp = (unsigned short*)outv;
            #pragma unroll
            for (int fm = 0; fm < FM; ++fm)
                #pragma unroll
                for (int fn = 0; fn < 2; ++fn)
                    #pragma unroll
                    for (int j = 0; j < 4; ++j) {
                        int r = wm * WR + fm * 16 + fr + j;
                        if (row0 + r < Mloc) {
                            int cc = col0 + wn * 32 + fn * 16 + fc;
                            float gv = acc1[fm][fn][j];
                            float uv = acc2[fm][fn][j];
                            float a = gv / (1.f + expf(-gv)) * uv;
                            outp[(size_t)(rb + row0 + r) * N + cc] = f2bf(a);
                        }
                    }
        } else if (ATOMIC) {
            float* outp = (float*)outv;
            #pragma unroll
            for (int fm = 0; fm < FM; ++fm)
                #pragma unroll
                for (int fn = 0; fn < 2; ++fn)
                    #pragma unroll
                    for (int j = 0; j < 4; ++j) {
                        int r = wm * WR + fm * 16 + fr + j;
                        if (row0 + r < Mloc) {
                            int tok = ltok[e * T_TOK + row0 + r];
                            float wr = lw[e * T_TOK + row0 + r];
                            int cc = col0 + wn * 32 + fn * 16 + fc;
                            atomicAdd(outp + (size_t)tok * N + cc, acc1[fm][fn][j] * wr);
                        }
                    }
        } else {
            float* outp = (float*)outv;
            #pragma unroll
            for (int fm = 0; fm < FM; ++fm)
                #pragma unroll
                for (int fn = 0; fn < 2; ++fn)
                    #pragma unroll
                    for (int j = 0; j < 4; ++j) {
                        int r = wm * WR + fm * 16 + fr + j;
                        if (row0 + r < Mloc) {
                            int cc = col0 + wn * 32 + fn * 16 + fc;
                            outp[(size_t)(row0 + r) * N + cc] = acc1[fm][fn][j];
                        }
                    }
        }
    }
}

// ---------------------------------------------------------------------------
extern "C" void kernel_launch(void* const* d_in, const int* in_sizes, int n_in,
                              void* d_out, int out_size, void* d_ws, size_t ws_size,
                              hipStream_t stream) {
    const float* x       = (const float*)d_in[0];
    const float* gate_w  = (const float*)d_in[1];
    const float* bias    = (const float*)d_in[2];
    const float* w_gate  = (const float*)d_in[3];
    const float* w_up    = (const float*)d_in[4];
    const float* w_down  = (const float*)d_in[5];
    const float* sw_gate = (const float*)d_in[6];
    const float* sw_up   = (const float*)d_in[7];
    const float* sw_down = (const float*)d_in[8];
    float* out = (float*)d_out;

    char* ws = (char*)d_ws;
    int*   topk_idx = (int*)ws;                                   // 32 KB
    float* topk_w   = (float*)(ws + 32768);                       // 32 KB
    int*   counts   = (int*)(ws + 65536);                         // 128 B
    int*   offsets  = (int*)(ws + 65536 + 128);                   // 128 B
    int*   ltok     = (int*)(ws + 65536 + 256);                   // 128 KB
    float* lw       = (float*)(ws + 65536 + 256 + 131072);        // 128 KB
    unsigned short* act_s = (unsigned short*)(ws + 65536 + 256 + 262144);  // 4 MB
    unsigned short* act_r = act_s + (size_t)T_TOK * IS_DIM;               // 16 MB

    route_k<<<T_TOK / 4, 256, 0, stream>>>(x, gate_w, bias, topk_idx, topk_w);
    build_k<<<E_NUM, 64, 0, stream>>>(topk_idx, topk_w, ltok, lw, counts);
    prefix_k<<<1, 64, 0, stream>>>(counts, offsets);

    // shared gate/up -> act_s (bf16): BM=128, all 256 blocks work
    gemm_k<1,0,0,0,128><<<dim3(8, 32, 1), 512, 0, stream>>>(
        x, sw_gate, sw_up, act_s, nullptr, nullptr, nullptr, nullptr,
        T_TOK, IS_DIM, H_DIM);
    // routed gate/up -> act_r (bf16): BM=256, exact grid + in-block m-loop
    gemm_k<1,1,0,0,256><<<dim3(1, 16, 32), 512, 0, stream>>>(
        x, w_gate, w_up, act_r, counts, offsets, ltok, lw,
        T_TOK, I_DIM, H_DIM);
    // shared down -> out (plain store, initializes out): BM=128
    gemm_k<0,0,1,0,128><<<dim3(8, 32, 1), 512, 0, stream>>>(
        act_s, sw_down, nullptr, out, nullptr, nullptr, nullptr, nullptr,
        T_TOK, H_DIM, IS_DIM);
    // routed down -> out (scaled atomicAdd): BM=256, exact grid
    gemm_k<0,1,1,1,256><<<dim3(1, 32, 32), 512, 0, stream>>>(
        act_r, w_down, nullptr, out, counts, offsets, ltok, lw,
        T_TOK, H_DIM, I_DIM);
}